// Round 13
// baseline (325.711 us; speedup 1.0000x reference)
//
#include <hip/hip_runtime.h>
#include <hip/hip_cooperative_groups.h>
#include <math.h>

namespace cg = cooperative_groups;

// SelfAttentionLayer B=4, N=2048, D=E=1024, fp32 in/out.
// out[b,j,e] = sum_i softmax_i(q_i . k_j / 32) * v[b,i,e]
// R17: ONE cooperative mega-kernel (256 blocks x 512 thr x 128KB LDS =
//      1 block/CU co-resident; grid.sync between stages). R15's proven
//      kernels become stages: prep -> qk+v -> scores -> pv. Eliminates
//      ~40-50us of launch/boundary drain measured as (wall 217 - kernel
//      sums ~162). R16's pv128/merge reverted (pv128 cost ~8us).
//
// ws (ushort): xb[8M] Wqkvt[3M] QKb[16M] Vtb[8M] Pb[16M] l[8192 f32].

typedef __bf16 bf16x8 __attribute__((ext_vector_type(8)));
typedef float f32x4 __attribute__((ext_vector_type(4)));

static __device__ __forceinline__ unsigned short f2bf(float f) {
    unsigned u = __float_as_uint(f);
    u += 0x7fff + ((u >> 16) & 1);   // round-to-nearest-even
    return (unsigned short)(u >> 16);
}

#define GLDS16(gptr, lptr)                                                            \
    __builtin_amdgcn_global_load_lds(                                                 \
        (const __attribute__((address_space(1))) void*)(gptr),                        \
        (__attribute__((address_space(3))) void*)(lptr), 16, 0, 0)

#define BARSYNC  __builtin_amdgcn_s_barrier()
#define WAITLGKM do { asm volatile("s_waitcnt lgkmcnt(0)" ::: "memory");    \
                      __builtin_amdgcn_sched_barrier(0); } while (0)

// ===================== 256x256 8-phase GEMM core =====================
// (R11-R15 structure, proven: conflicts 0, passed refcheck 5x.)
__device__ __forceinline__ void gemm256_core(
    const unsigned short* __restrict__ Ab,   // + gm0*ld
    const unsigned short* __restrict__ Bb,   // + gn0*ld
    const long ld, unsigned short* lds, f32x4 acc[8][4])
{
    const int tid  = threadIdx.x;
    const int w    = tid >> 6;
    const int lane = tid & 63;

    const int r  = lane >> 3;
    const int s  = lane & 7;
    const int cg = (s ^ r) * 8;

    const int fr    = lane & 15;
    const int quad  = lane >> 4;
    const int sw    = fr & 7;
    const int arow0 = (w >> 2) * 128;
    const int brow0 = (w & 3) * 64;

#define STG_A(t, mh, buf) do {                                              \
    const int rb_ = (w >> 2) * 128 + (mh) * 64 + (w & 3) * 16;              \
    const unsigned short* g_ = Ab + (long)(rb_ + r) * ld + (long)(t) * 64 + cg; \
    unsigned short* d_ = lds + (buf) * 16384 + rb_ * 64;                    \
    GLDS16(g_, d_); GLDS16(g_ + 8 * ld, d_ + 512); } while (0)
#define STG_B(t, nh, buf) do {                                              \
    const int rb_ = (w >> 1) * 64 + (nh) * 32 + (w & 1) * 16;               \
    const unsigned short* g_ = Bb + (long)(rb_ + r) * ld + (long)(t) * 64 + cg; \
    unsigned short* d_ = lds + 32768 + (buf) * 16384 + rb_ * 64;            \
    GLDS16(g_, d_); GLDS16(g_ + 8 * ld, d_ + 512); } while (0)

    bf16x8 af[4][2], bfA[2][2], bfB[2][2];
#define LOADA(buf, mh) do {                                                 \
    _Pragma("unroll") for (int ks_ = 0; ks_ < 2; ks_++)                     \
    _Pragma("unroll") for (int i_ = 0; i_ < 4; i_++)                        \
        af[i_][ks_] = *(const bf16x8*)&lds[(buf) * 16384 +                  \
            (arow0 + (mh) * 64 + i_ * 16 + fr) * 64 +                       \
            ((ks_ * 4 + quad) ^ sw) * 8]; } while (0)
#define LOADB(BF, buf, nh) do {                                             \
    _Pragma("unroll") for (int ks_ = 0; ks_ < 2; ks_++)                     \
    _Pragma("unroll") for (int j_ = 0; j_ < 2; j_++)                        \
        BF[j_][ks_] = *(const bf16x8*)&lds[32768 + (buf) * 16384 +          \
            (brow0 + (nh) * 32 + j_ * 16 + fr) * 64 +                       \
            ((ks_ * 4 + quad) ^ sw) * 8]; } while (0)

#define MFMA16(mh, nh, BF) do {                                             \
    __builtin_amdgcn_s_setprio(1);                                          \
    _Pragma("unroll") for (int ks_ = 0; ks_ < 2; ks_++)                     \
    _Pragma("unroll") for (int i_ = 0; i_ < 4; i_++)                        \
    _Pragma("unroll") for (int j_ = 0; j_ < 2; j_++)                        \
        acc[(mh) * 4 + i_][(nh) * 2 + j_] =                                 \
            __builtin_amdgcn_mfma_f32_16x16x32_bf16(                        \
                af[i_][ks_], BF[j_][ks_],                                   \
                acc[(mh) * 4 + i_][(nh) * 2 + j_], 0, 0, 0);                \
    __builtin_amdgcn_s_setprio(0); } while (0)

#pragma unroll
    for (int i = 0; i < 8; i++)
#pragma unroll
        for (int j = 0; j < 4; j++) acc[i][j] = f32x4{0.f, 0.f, 0.f, 0.f};

    // prologue: buf0 <- tile0 (4 units); buf1 <- tile1 partial (mh0, nh1)
    STG_A(0, 0, 0); STG_A(0, 1, 0); STG_B(0, 0, 0); STG_B(0, 1, 0);
    STG_A(1, 0, 1); STG_B(1, 1, 1);
    asm volatile("s_waitcnt vmcnt(4)" ::: "memory");   // buf0 complete
    BARSYNC;

#pragma unroll 1
    for (int i = 0; i < 8; ++i) {
        const int t1 = 2 * i + 1;
        const int t2 = (2 * i + 2) & 15;   // dummy re-read on last iter (safe)
        const int t3 = (2 * i + 3) & 15;
        // ph1 (buf0, mh0, nh0)
        LOADA(0, 0); LOADB(bfA, 0, 0); STG_B(t1, 0, 1);
        BARSYNC; WAITLGKM; MFMA16(0, 0, bfA); BARSYNC;
        // ph2 (buf0, mh0, nh1)
        LOADB(bfB, 0, 1); STG_A(t1, 1, 1);
        BARSYNC; WAITLGKM; MFMA16(0, 1, bfB); BARSYNC;
        // ph3 (buf0, mh1, nh1)
        LOADA(0, 1); STG_A(t2, 0, 0);
        BARSYNC; WAITLGKM; MFMA16(1, 1, bfB); BARSYNC;
        // ph4 (buf0, mh1, nh0) reuses bfA + drain: buf1 <- t1 complete
        STG_B(t2, 1, 0);
        BARSYNC; MFMA16(1, 0, bfA);
        asm volatile("s_waitcnt vmcnt(4)" ::: "memory"); BARSYNC;
        // ph5 (buf1, mh0, nh0)
        LOADA(1, 0); LOADB(bfA, 1, 0); STG_A(t2, 1, 0);
        BARSYNC; WAITLGKM; MFMA16(0, 0, bfA); BARSYNC;
        // ph6 (buf1, mh0, nh1)
        LOADB(bfB, 1, 1); STG_B(t2, 0, 0);
        BARSYNC; WAITLGKM; MFMA16(0, 1, bfB); BARSYNC;
        // ph7 (buf1, mh1, nh1)
        LOADA(1, 1); STG_A(t3, 0, 1);
        BARSYNC; WAITLGKM; MFMA16(1, 1, bfB); BARSYNC;
        // ph8 (buf1, mh1, nh0) reuses bfA + drain: buf0 <- t2 complete
        STG_B(t3, 1, 1);
        BARSYNC; MFMA16(1, 0, bfA);
        asm volatile("s_waitcnt vmcnt(4)" ::: "memory"); BARSYNC;
    }
    asm volatile("s_waitcnt vmcnt(0)" ::: "memory");   // drain dummy stages

#undef STG_A
#undef STG_B
#undef LOADA
#undef LOADB
#undef MFMA16
}

// ===================== 128x256 8-phase V core =====================
// (R14/R15 structure, passed refcheck.) 512 threads, LDS 96KB.
__device__ __forceinline__ void gemm_v128_core(
    const unsigned short* __restrict__ Ab,   // xb + gm0*1024
    const unsigned short* __restrict__ Bb,   // Wvt + gn0*1024
    unsigned short* lds, f32x4 acc[4][4])
{
    const int tid  = threadIdx.x;
    const int w    = tid >> 6;
    const int lane = tid & 63;

    const int r  = lane >> 3;
    const int s  = lane & 7;
    const int cg = (s ^ r) * 8;

    const int fr    = lane & 15;
    const int quad  = lane >> 4;
    const int sw    = fr & 7;
    const int arow0 = (w >> 2) * 64;
    const int brow0 = (w & 3) * 64;

#define STG_VA(t, mh, buf) do {                                             \
    const int rb_ = (w >> 2) * 64 + (mh) * 32 + (w & 3) * 8;                \
    const unsigned short* g_ = Ab + (long)(rb_ + r) * 1024 + (long)(t) * 64 + cg; \
    unsigned short* d_ = lds + (buf) * 8192 + rb_ * 64;                     \
    GLDS16(g_, d_); } while (0)
#define STG_VB(t, nh, buf) do {                                             \
    const int rb_ = (w >> 1) * 64 + (nh) * 32 + (w & 1) * 16;               \
    const unsigned short* g_ = Bb + (long)(rb_ + r) * 1024 + (long)(t) * 64 + cg; \
    unsigned short* d_ = lds + 16384 + (buf) * 16384 + rb_ * 64;            \
    GLDS16(g_, d_); GLDS16(g_ + 8 * 1024, d_ + 512); } while (0)

    bf16x8 af[2][2], bfA[2][2], bfB[2][2];
#define LOADVA(buf, mh) do {                                                \
    _Pragma("unroll") for (int ks_ = 0; ks_ < 2; ks_++)                     \
    _Pragma("unroll") for (int i_ = 0; i_ < 2; i_++)                        \
        af[i_][ks_] = *(const bf16x8*)&lds[(buf) * 8192 +                   \
            (arow0 + (mh) * 32 + i_ * 16 + fr) * 64 +                       \
            ((ks_ * 4 + quad) ^ sw) * 8]; } while (0)
#define LOADVB(BF, buf, nh) do {                                            \
    _Pragma("unroll") for (int ks_ = 0; ks_ < 2; ks_++)                     \
    _Pragma("unroll") for (int j_ = 0; j_ < 2; j_++)                        \
        BF[j_][ks_] = *(const bf16x8*)&lds[16384 + (buf) * 16384 +          \
            (brow0 + (nh) * 32 + j_ * 16 + fr) * 64 +                       \
            ((ks_ * 4 + quad) ^ sw) * 8]; } while (0)

#define MFMA_V(mh, nh, BF) do {                                             \
    __builtin_amdgcn_s_setprio(1);                                          \
    _Pragma("unroll") for (int ks_ = 0; ks_ < 2; ks_++)                     \
    _Pragma("unroll") for (int i_ = 0; i_ < 2; i_++)                        \
    _Pragma("unroll") for (int j_ = 0; j_ < 2; j_++)                        \
        acc[(mh) * 2 + i_][(nh) * 2 + j_] =                                 \
            __builtin_amdgcn_mfma_f32_16x16x32_bf16(                        \
                af[i_][ks_], BF[j_][ks_],                                   \
                acc[(mh) * 2 + i_][(nh) * 2 + j_], 0, 0, 0);                \
    __builtin_amdgcn_s_setprio(0); } while (0)

#pragma unroll
    for (int i = 0; i < 4; i++)
#pragma unroll
        for (int j = 0; j < 4; j++) acc[i][j] = f32x4{0.f, 0.f, 0.f, 0.f};

    // prologue: buf0 <- tile0 (6 loads); buf1 <- tile1 partial (A-mh0 1, B-nh1 2)
    STG_VA(0, 0, 0); STG_VA(0, 1, 0); STG_VB(0, 0, 0); STG_VB(0, 1, 0);
    STG_VA(1, 0, 1); STG_VB(1, 1, 1);
    asm volatile("s_waitcnt vmcnt(3)" ::: "memory");   // buf0 complete
    BARSYNC;

#pragma unroll 1
    for (int i = 0; i < 8; ++i) {
        const int t1 = 2 * i + 1;
        const int t2 = (2 * i + 2) & 15;   // dummy re-read on last iter (safe)
        const int t3 = (2 * i + 3) & 15;
        // ph1 (buf0, mh0, nh0)
        LOADVA(0, 0); LOADVB(bfA, 0, 0); STG_VB(t1, 0, 1);
        BARSYNC; WAITLGKM; MFMA_V(0, 0, bfA); BARSYNC;
        // ph2 (buf0, mh0, nh1)
        LOADVB(bfB, 0, 1); STG_VA(t1, 1, 1);
        BARSYNC; WAITLGKM; MFMA_V(0, 1, bfB); BARSYNC;
        // ph3 (buf0, mh1, nh1)
        LOADVA(0, 1); STG_VA(t2, 0, 0);
        BARSYNC; WAITLGKM; MFMA_V(1, 1, bfB); BARSYNC;
        // ph4 (buf0, mh1, nh0) reuses bfA + drain: buf1 <- t1 complete
        STG_VB(t2, 1, 0);
        BARSYNC; MFMA_V(1, 0, bfA);
        asm volatile("s_waitcnt vmcnt(3)" ::: "memory"); BARSYNC;
        // ph5 (buf1, mh0, nh0)
        LOADVA(1, 0); LOADVB(bfA, 1, 0); STG_VA(t2, 1, 0);
        BARSYNC; WAITLGKM; MFMA_V(0, 0, bfA); BARSYNC;
        // ph6 (buf1, mh0, nh1)
        LOADVB(bfB, 1, 1); STG_VB(t2, 0, 0);
        BARSYNC; WAITLGKM; MFMA_V(0, 1, bfB); BARSYNC;
        // ph7 (buf1, mh1, nh1)
        LOADVA(1, 1); STG_VA(t3, 0, 1);
        BARSYNC; WAITLGKM; MFMA_V(1, 1, bfB); BARSYNC;
        // ph8 (buf1, mh1, nh0) reuses bfA + drain: buf0 <- t2 complete
        STG_VB(t3, 1, 1);
        BARSYNC; MFMA_V(1, 0, bfA);
        asm volatile("s_waitcnt vmcnt(3)" ::: "memory"); BARSYNC;
    }
    asm volatile("s_waitcnt vmcnt(0)" ::: "memory");   // drain dummy stages

#undef STG_VA
#undef STG_VB
#undef LOADVA
#undef LOADVB
#undef MFMA_V
}

// ===================== 256x128 8-phase PV core =====================
// (R13-R15 structure, passed refcheck.) LDS 96KB. WAITV(3) at ph4/ph8.
__device__ __forceinline__ void pv256_core(
    const unsigned short* __restrict__ Ab,   // P + bz*4M + gm0*2048
    const unsigned short* __restrict__ Bb,   // Vt + gn0*8192 + bz*2048
    unsigned short* lds, f32x4 acc[8][2])
{
    const int tid  = threadIdx.x;
    const int w    = tid >> 6;
    const int lane = tid & 63;

    const int r  = lane >> 3;
    const int s  = lane & 7;
    const int cg = (s ^ r) * 8;

    const int fr    = lane & 15;
    const int quad  = lane >> 4;
    const int sw    = fr & 7;
    const int arow0 = (w >> 2) * 128;
    const int brow0 = (w & 3) * 32;

#define STG_PA(t, mh, buf) do {                                             \
    const int rb_ = (w >> 2) * 128 + (mh) * 64 + (w & 3) * 16;              \
    const unsigned short* g_ = Ab + (long)(rb_ + r) * 2048 + (long)(t) * 64 + cg; \
    unsigned short* d_ = lds + (buf) * 16384 + rb_ * 64;                    \
    GLDS16(g_, d_); GLDS16(g_ + 8 * 2048, d_ + 512); } while (0)
#define STG_PB(t, nh, buf) do {                                             \
    const int rb_ = (w & 3) * 32 + (nh) * 16 + (w >> 2) * 8;                \
    const unsigned short* g_ = Bb + (long)(rb_ + r) * 8192 + (long)(t) * 64 + cg; \
    unsigned short* d_ = lds + 32768 + (buf) * 8192 + rb_ * 64;             \
    GLDS16(g_, d_); } while (0)

    bf16x8 af[4][2], bfA[2], bfB[2];
#define LOADPA(buf, mh) do {                                                \
    _Pragma("unroll") for (int ks_ = 0; ks_ < 2; ks_++)                     \
    _Pragma("unroll") for (int i_ = 0; i_ < 4; i_++)                        \
        af[i_][ks_] = *(const bf16x8*)&lds[(buf) * 16384 +                  \
            (arow0 + (mh) * 64 + i_ * 16 + fr) * 64 +                       \
            ((ks_ * 4 + quad) ^ sw) * 8]; } while (0)
#define LOADPB(BF, buf, nh) do {                                            \
    _Pragma("unroll") for (int ks_ = 0; ks_ < 2; ks_++)                     \
        BF[ks_] = *(const bf16x8*)&lds[32768 + (buf) * 8192 +               \
            (brow0 + (nh) * 16 + fr) * 64 +                                 \
            ((ks_ * 4 + quad) ^ sw) * 8]; } while (0)

#define MFMA8(mh, nh, BF) do {                                              \
    __builtin_amdgcn_s_setprio(1);                                          \
    _Pragma("unroll") for (int ks_ = 0; ks_ < 2; ks_++)                     \
    _Pragma("unroll") for (int i_ = 0; i_ < 4; i_++)                        \
        acc[(mh) * 4 + i_][nh] = __builtin_amdgcn_mfma_f32_16x16x32_bf16(   \
            af[i_][ks_], BF[ks_], acc[(mh) * 4 + i_][nh], 0, 0, 0);         \
    __builtin_amdgcn_s_setprio(0); } while (0)

#pragma unroll
    for (int i = 0; i < 8; i++)
#pragma unroll
        for (int j = 0; j < 2; j++) acc[i][j] = f32x4{0.f, 0.f, 0.f, 0.f};

    // prologue: buf0 <- tile0 (6 loads); buf1 <- tile1 partial (A-mh0 2, B-nh1 1)
    STG_PA(0, 0, 0); STG_PA(0, 1, 0); STG_PB(0, 0, 0); STG_PB(0, 1, 0);
    STG_PA(1, 0, 1); STG_PB(1, 1, 1);
    asm volatile("s_waitcnt vmcnt(3)" ::: "memory");   // buf0 complete
    BARSYNC;

#pragma unroll 1
    for (int i = 0; i < 16; ++i) {
        const int t1 = 2 * i + 1;
        const int t2 = (2 * i + 2) & 31;   // dummy re-read on last iter (safe)
        const int t3 = (2 * i + 3) & 31;
        // ph1 (buf0, mh0, nh0)
        LOADPA(0, 0); LOADPB(bfA, 0, 0); STG_PB(t1, 0, 1);
        BARSYNC; WAITLGKM; MFMA8(0, 0, bfA); BARSYNC;
        // ph2 (buf0, mh0, nh1)
        LOADPB(bfB, 0, 1); STG_PA(t1, 1, 1);
        BARSYNC; WAITLGKM; MFMA8(0, 1, bfB); BARSYNC;
        // ph3 (buf0, mh1, nh1)
        LOADPA(0, 1); STG_PA(t2, 0, 0);
        BARSYNC; WAITLGKM; MFMA8(1, 1, bfB); BARSYNC;
        // ph4 (buf0, mh1, nh0) reuses bfA + drain: buf1 <- t1 complete
        STG_PB(t2, 1, 0);
        BARSYNC; MFMA8(1, 0, bfA);
        asm volatile("s_waitcnt vmcnt(3)" ::: "memory"); BARSYNC;
        // ph5 (buf1, mh0, nh0)
        LOADPA(1, 0); LOADPB(bfA, 1, 0); STG_PA(t2, 1, 0);
        BARSYNC; WAITLGKM; MFMA8(0, 0, bfA); BARSYNC;
        // ph6 (buf1, mh0, nh1)
        LOADPB(bfB, 1, 1); STG_PB(t2, 0, 0);
        BARSYNC; WAITLGKM; MFMA8(0, 1, bfB); BARSYNC;
        // ph7 (buf1, mh1, nh1)
        LOADPA(1, 1); STG_PA(t3, 0, 1);
        BARSYNC; WAITLGKM; MFMA8(1, 1, bfB); BARSYNC;
        // ph8 (buf1, mh1, nh0) reuses bfA + drain: buf0 <- t2 complete
        STG_PB(t3, 1, 1);
        BARSYNC; MFMA8(1, 0, bfA);
        asm volatile("s_waitcnt vmcnt(3)" ::: "memory"); BARSYNC;
    }
    asm volatile("s_waitcnt vmcnt(0)" ::: "memory");   // drain dummy stages

#undef STG_PA
#undef STG_PB
#undef LOADPA
#undef LOADPB
#undef MFMA8
}

// ===================== cooperative mega-kernel =====================
// 256 blocks x 512 threads x 128KB LDS = 1 block/CU, all co-resident.
// stage0: prep (x bf16-convert, W transpose, l zero)   -> grid.sync
// stage1: qk-tile(b) then v-tile(b) (independent)      -> grid.sync
// stage2: scores-tile(b)                               -> grid.sync
// stage3: pv-tile(b)
__global__ __launch_bounds__(512, 2) void mega_attn(
    const float* __restrict__ x,
    const float* __restrict__ Wq, const float* __restrict__ Wk,
    const float* __restrict__ Wv, float* __restrict__ out,
    unsigned short* __restrict__ ws)
{
    __shared__ unsigned short lds[65536];   // 128 KB, reused per stage

    const long M1 = 1024 * 1024;
    unsigned short* xb    = ws;
    unsigned short* Wqkvt = ws + 8 * M1;
    unsigned short* QKb   = Wqkvt + 3 * M1;
    unsigned short* Vtb   = QKb + 16 * M1;
    unsigned short* Pb0   = Vtb + 8 * M1;
    float* l              = (float*)(Pb0 + 16 * M1);

    const int b   = blockIdx.x;
    const int tid = threadIdx.x;
    const int w = tid >> 6, lane = tid & 63;
    const int fr = lane & 15, quad = lane >> 4;

    cg::grid_group grid = cg::this_grid();

    // ---------------- stage 0: prep ----------------
    {
        // x convert: 2M float4, 16 per thread, coalesced
        const float4* x4 = (const float4*)x;
        ushort4* xb4 = (ushort4*)xb;
#pragma unroll
        for (int i = 0; i < 16; i++) {
            const long idx = (long)i * (256 * 512) + (long)b * 512 + tid;
            float4 v = x4[idx];
            ushort4 o;
            o.x = f2bf(v.x); o.y = f2bf(v.y); o.z = f2bf(v.z); o.w = f2bf(v.w);
            xb4[idx] = o;
        }
        // W transpose: 3072 32x32 tiles; 12 per block, 2 concurrently
        float* tf = (float*)lds;              // [2][32][33] floats = 8448 B
        const int sub = tid >> 8;             // 0..1
        const int t2  = tid & 255;
        const int tx  = t2 & 31;
        const int ty  = (t2 >> 5) * 4;
#pragma unroll 1
        for (int stp = 0; stp < 6; stp++) {
            const int tix = b * 12 + stp * 2 + sub;
            const int wsel = tix >> 10;
            const int t10  = tix & 1023;
            const float* W = (wsel == 0) ? Wq : (wsel == 1) ? Wk : Wv;
            unsigned short* Wt = Wqkvt + (long)wsel * M1;
            const int bx = (t10 & 31) * 32;
            const int by = (t10 >> 5) * 32;
            float* tt = tf + sub * (32 * 33);
#pragma unroll
            for (int j = 0; j < 4; j++)
                tt[(ty + j) * 33 + tx] = W[(long)(by + ty + j) * 1024 + bx + tx];
            __syncthreads();
#pragma unroll
            for (int j = 0; j < 4; j++)
                Wt[(long)(bx + ty + j) * 1024 + by + tx] = f2bf(tt[tx * 33 + ty + j]);
            __syncthreads();
        }
        // l zero: 8192 floats / 256 blocks
        if (tid < 32) l[b * 32 + tid] = 0.f;
    }
    grid.sync();

    // ---------------- stage 1: qk-tile(b), then v-tile(b) ----------------
    {
        const int xcd = b & 7;
        const int pos = b >> 3;
        // qk (swapped: A=W rows f, B=x rows m) -> ushort4 to QK[m][f]
        {
            const long gm0 = (long)(pos >> 2) * 256;            // feature f
            const long gn0 = (long)(xcd * 4 + (pos & 3)) * 256; // token m
            f32x4 acc[8][4];
            gemm256_core(Wqkvt + gm0 * 1024, xb + gn0 * 1024, 1024, lds, acc);
            const int wm = (w >> 2) * 128, wn = (w & 3) * 64;
#pragma unroll
            for (int mi = 0; mi < 8; mi++) {
                const long rb = gm0 + wm + (mi >> 2) * 64 + (mi & 3) * 16 + quad * 4;
#pragma unroll
                for (int n = 0; n < 4; n++) {
                    const long cb = gn0 + wn + n * 16 + fr;
                    ushort4 o;
                    o.x = f2bf(acc[mi][n][0]);
                    o.y = f2bf(acc[mi][n][1]);
                    o.z = f2bf(acc[mi][n][2]);
                    o.w = f2bf(acc[mi][n][3]);
                    *(ushort4*)&QKb[cb * 2048L + rb] = o;
                }
            }
        }
        __syncthreads();
        // v: Vt[e*8192 + m]
        {
            const long gm0 = (long)(xcd * 8 + (pos & 7)) * 128;
            const long gn0 = (long)(pos >> 3) * 256;
            f32x4 acc[4][4];
            gemm_v128_core(xb + gm0 * 1024, Wqkvt + 2 * M1 + gn0 * 1024, lds, acc);
            const int wm = (w >> 2) * 64, wn = (w & 3) * 64;
#pragma unroll
            for (int ai = 0; ai < 4; ai++) {
                const long rb = gm0 + wm + ai * 16 + quad * 4;
#pragma unroll
                for (int aj = 0; aj < 4; aj++) {
                    const long ce = gn0 + wn + aj * 16 + fr;
                    ushort4 o;
                    o.x = f2bf(acc[ai][aj][0]);
                    o.y = f2bf(acc[ai][aj][1]);
                    o.z = f2bf(acc[ai][aj][2]);
                    o.w = f2bf(acc[ai][aj][3]);
                    *(ushort4*)&Vtb[ce * 8192L + rb] = o;
                }
            }
        }
    }
    grid.sync();

    // ---------------- stage 2: scores-tile(b) ----------------
    {
        const int xcd = b & 7;
        const int pos = b >> 3;
        const int bz  = xcd >> 1;
        const long gm0 = (long)((xcd & 1) * 4 + (pos >> 3)) * 256;  // i (Q rows)
        const long gn0 = (long)(pos & 7) * 256;                     // j (K rows)

        const unsigned short* Ab = QKb + (long)bz * 2048 * 2048 + gm0 * 2048;         // Q
        const unsigned short* Bb = QKb + (long)bz * 2048 * 2048 + 1024 + gn0 * 2048;  // K

        f32x4 acc[8][4];
        gemm256_core(Ab, Bb, 2048, lds, acc);

        const int wm = (w >> 2) * 128, wn = (w & 3) * 64;
        unsigned short* Pb = Pb0 + (long)bz * 2048 * 2048;
        float* lb = l + (long)bz * 2048;
        const float scale = 1.0f / 32.0f;

        float colsum[4] = {0.f, 0.f, 0.f, 0.f};
#pragma unroll
        for (int mi = 0; mi < 8; mi++) {
            const long rb = gm0 + wm + (mi >> 2) * 64 + (mi & 3) * 16 + quad * 4;  // i
#pragma unroll
            for (int n = 0; n < 4; n++) {
                const long cb = gn0 + wn + n * 16 + fr;                            // j
                float e0 = __expf(acc[mi][n][0] * scale);
                float e1 = __expf(acc[mi][n][1] * scale);
                float e2 = __expf(acc[mi][n][2] * scale);
                float e3 = __expf(acc[mi][n][3] * scale);
                colsum[n] += (e0 + e1) + (e2 + e3);
                ushort4 o;
                o.x = f2bf(e0); o.y = f2bf(e1); o.z = f2bf(e2); o.w = f2bf(e3);
                *(ushort4*)&Pb[cb * 2048L + rb] = o;
            }
        }
#pragma unroll
        for (int n = 0; n < 4; n++) {
            colsum[n] += __shfl_xor(colsum[n], 16);
            colsum[n] += __shfl_xor(colsum[n], 32);
        }
        if (quad == 0) {
#pragma unroll
            for (int n = 0; n < 4; n++)
                atomicAdd(&lb[gn0 + wn + n * 16 + fr], colsum[n]);
        }
    }
    grid.sync();

    // ---------------- stage 3: pv-tile(b) ----------------
    {
        const int xcd = b & 7;
        const int pos = b >> 3;
        const int bz  = xcd >> 1;
        const long gm0 = (long)((xcd & 1) * 4 + (pos >> 3)) * 256;  // j
        const long gn0 = (long)(pos & 7) * 128;                     // e

        const unsigned short* Ab = Pb0 + (long)bz * 2048 * 2048 + gm0 * 2048;
        const unsigned short* Bb = Vtb + gn0 * 8192 + (long)bz * 2048;

        f32x4 acc[8][2];
        pv256_core(Ab, Bb, lds, acc);

        const int wm = (w >> 2) * 128, wn = (w & 3) * 32;
        float* Ob = out + (long)bz * 2048 * 1024;
        const float* lb = l + (long)bz * 2048;
#pragma unroll
        for (int mi = 0; mi < 8; mi++) {
            const long rb = gm0 + wm + (mi >> 2) * 64 + (mi & 3) * 16 + quad * 4;
            float inv[4];
#pragma unroll
            for (int rr = 0; rr < 4; rr++) inv[rr] = 1.0f / lb[rb + rr];
#pragma unroll
            for (int nj = 0; nj < 2; nj++) {
                const long cb = gn0 + wn + nj * 16 + fr;
#pragma unroll
                for (int rr = 0; rr < 4; rr++)
                    Ob[(rb + rr) * 1024L + cb] = acc[mi][nj][rr] * inv[rr];
            }
        }
    }
}

extern "C" void kernel_launch(void* const* d_in, const int* in_sizes, int n_in,
                              void* d_out, int out_size, void* d_ws,
                              size_t ws_size, hipStream_t stream)
{
    const float* x  = (const float*)d_in[0];
    const float* Wq = (const float*)d_in[1];
    const float* Wk = (const float*)d_in[2];
    const float* Wv = (const float*)d_in[3];
    float* out = (float*)d_out;
    unsigned short* u = (unsigned short*)d_ws;

    void* args[] = {(void*)&x, (void*)&Wq, (void*)&Wk, (void*)&Wv,
                    (void*)&out, (void*)&u};
    hipLaunchCooperativeKernel((const void*)mega_attn, dim3(256), dim3(512),
                               args, 0, stream);
}

// Round 14
// 220.345 us; speedup vs baseline: 1.4782x; 1.4782x over previous
//
#include <hip/hip_runtime.h>
#include <math.h>

// SelfAttentionLayer B=4, N=2048, D=E=1024, fp32 in/out.
// out[b,j,e] = sum_i softmax_i(q_i . k_j / 32) * v[b,i,e]
// R18: best verified combination. R17's cooperative mega-kernel regressed
//      (grid.sync ~25-30us each + cold LDS restarts; 244us in-kernel).
//      R16 decomposition: qkv merge was +9us WIN (61.4 vs 40+19+11),
//      pv128 was the loss. So: prep + qkv_split(R16) + scores256(R15) +
//      pv256(R13-15) = 4 launches, all components previously passed.
//
// ws (ushort): xb[8M] Wqkvt[3M] QKb[16M] Vtb[8M] Pb[16M] l[8192 f32].

typedef __bf16 bf16x8 __attribute__((ext_vector_type(8)));
typedef float f32x4 __attribute__((ext_vector_type(4)));

static __device__ __forceinline__ unsigned short f2bf(float f) {
    unsigned u = __float_as_uint(f);
    u += 0x7fff + ((u >> 16) & 1);   // round-to-nearest-even
    return (unsigned short)(u >> 16);
}

#define GLDS16(gptr, lptr)                                                            \
    __builtin_amdgcn_global_load_lds(                                                 \
        (const __attribute__((address_space(1))) void*)(gptr),                        \
        (__attribute__((address_space(3))) void*)(lptr), 16, 0, 0)

#define BARSYNC  __builtin_amdgcn_s_barrier()
#define WAITLGKM do { asm volatile("s_waitcnt lgkmcnt(0)" ::: "memory");    \
                      __builtin_amdgcn_sched_barrier(0); } while (0)

// ===================== 256x256 8-phase GEMM core =====================
// (R11-R16 structure, proven: conflicts 0, passed refcheck 6x.)
__device__ __forceinline__ void gemm256_core(
    const unsigned short* __restrict__ Ab,   // + gm0*ld
    const unsigned short* __restrict__ Bb,   // + gn0*ld
    const long ld, unsigned short* lds, f32x4 acc[8][4])
{
    const int tid  = threadIdx.x;
    const int w    = tid >> 6;
    const int lane = tid & 63;

    const int r  = lane >> 3;
    const int s  = lane & 7;
    const int cg = (s ^ r) * 8;

    const int fr    = lane & 15;
    const int quad  = lane >> 4;
    const int sw    = fr & 7;
    const int arow0 = (w >> 2) * 128;
    const int brow0 = (w & 3) * 64;

#define STG_A(t, mh, buf) do {                                              \
    const int rb_ = (w >> 2) * 128 + (mh) * 64 + (w & 3) * 16;              \
    const unsigned short* g_ = Ab + (long)(rb_ + r) * ld + (long)(t) * 64 + cg; \
    unsigned short* d_ = lds + (buf) * 16384 + rb_ * 64;                    \
    GLDS16(g_, d_); GLDS16(g_ + 8 * ld, d_ + 512); } while (0)
#define STG_B(t, nh, buf) do {                                              \
    const int rb_ = (w >> 1) * 64 + (nh) * 32 + (w & 1) * 16;               \
    const unsigned short* g_ = Bb + (long)(rb_ + r) * ld + (long)(t) * 64 + cg; \
    unsigned short* d_ = lds + 32768 + (buf) * 16384 + rb_ * 64;            \
    GLDS16(g_, d_); GLDS16(g_ + 8 * ld, d_ + 512); } while (0)

    bf16x8 af[4][2], bfA[2][2], bfB[2][2];
#define LOADA(buf, mh) do {                                                 \
    _Pragma("unroll") for (int ks_ = 0; ks_ < 2; ks_++)                     \
    _Pragma("unroll") for (int i_ = 0; i_ < 4; i_++)                        \
        af[i_][ks_] = *(const bf16x8*)&lds[(buf) * 16384 +                  \
            (arow0 + (mh) * 64 + i_ * 16 + fr) * 64 +                       \
            ((ks_ * 4 + quad) ^ sw) * 8]; } while (0)
#define LOADB(BF, buf, nh) do {                                             \
    _Pragma("unroll") for (int ks_ = 0; ks_ < 2; ks_++)                     \
    _Pragma("unroll") for (int j_ = 0; j_ < 2; j_++)                        \
        BF[j_][ks_] = *(const bf16x8*)&lds[32768 + (buf) * 16384 +          \
            (brow0 + (nh) * 32 + j_ * 16 + fr) * 64 +                       \
            ((ks_ * 4 + quad) ^ sw) * 8]; } while (0)

#define MFMA16(mh, nh, BF) do {                                             \
    __builtin_amdgcn_s_setprio(1);                                          \
    _Pragma("unroll") for (int ks_ = 0; ks_ < 2; ks_++)                     \
    _Pragma("unroll") for (int i_ = 0; i_ < 4; i_++)                        \
    _Pragma("unroll") for (int j_ = 0; j_ < 2; j_++)                        \
        acc[(mh) * 4 + i_][(nh) * 2 + j_] =                                 \
            __builtin_amdgcn_mfma_f32_16x16x32_bf16(                        \
                af[i_][ks_], BF[j_][ks_],                                   \
                acc[(mh) * 4 + i_][(nh) * 2 + j_], 0, 0, 0);                \
    __builtin_amdgcn_s_setprio(0); } while (0)

#pragma unroll
    for (int i = 0; i < 8; i++)
#pragma unroll
        for (int j = 0; j < 4; j++) acc[i][j] = f32x4{0.f, 0.f, 0.f, 0.f};

    // prologue: buf0 <- tile0 (4 units); buf1 <- tile1 partial (mh0, nh1)
    STG_A(0, 0, 0); STG_A(0, 1, 0); STG_B(0, 0, 0); STG_B(0, 1, 0);
    STG_A(1, 0, 1); STG_B(1, 1, 1);
    asm volatile("s_waitcnt vmcnt(4)" ::: "memory");   // buf0 complete
    BARSYNC;

#pragma unroll 1
    for (int i = 0; i < 8; ++i) {
        const int t1 = 2 * i + 1;
        const int t2 = (2 * i + 2) & 15;   // dummy re-read on last iter (safe)
        const int t3 = (2 * i + 3) & 15;
        // ph1 (buf0, mh0, nh0)
        LOADA(0, 0); LOADB(bfA, 0, 0); STG_B(t1, 0, 1);
        BARSYNC; WAITLGKM; MFMA16(0, 0, bfA); BARSYNC;
        // ph2 (buf0, mh0, nh1)
        LOADB(bfB, 0, 1); STG_A(t1, 1, 1);
        BARSYNC; WAITLGKM; MFMA16(0, 1, bfB); BARSYNC;
        // ph3 (buf0, mh1, nh1)
        LOADA(0, 1); STG_A(t2, 0, 0);
        BARSYNC; WAITLGKM; MFMA16(1, 1, bfB); BARSYNC;
        // ph4 (buf0, mh1, nh0) reuses bfA + drain: buf1 <- t1 complete
        STG_B(t2, 1, 0);
        BARSYNC; MFMA16(1, 0, bfA);
        asm volatile("s_waitcnt vmcnt(4)" ::: "memory"); BARSYNC;
        // ph5 (buf1, mh0, nh0)
        LOADA(1, 0); LOADB(bfA, 1, 0); STG_A(t2, 1, 0);
        BARSYNC; WAITLGKM; MFMA16(0, 0, bfA); BARSYNC;
        // ph6 (buf1, mh0, nh1)
        LOADB(bfB, 1, 1); STG_B(t2, 0, 0);
        BARSYNC; WAITLGKM; MFMA16(0, 1, bfB); BARSYNC;
        // ph7 (buf1, mh1, nh1)
        LOADA(1, 1); STG_A(t3, 0, 1);
        BARSYNC; WAITLGKM; MFMA16(1, 1, bfB); BARSYNC;
        // ph8 (buf1, mh1, nh0) reuses bfA + drain: buf0 <- t2 complete
        STG_B(t3, 1, 1);
        BARSYNC; MFMA16(1, 0, bfA);
        asm volatile("s_waitcnt vmcnt(4)" ::: "memory"); BARSYNC;
    }
    asm volatile("s_waitcnt vmcnt(0)" ::: "memory");   // drain dummy stages

#undef STG_A
#undef STG_B
#undef LOADA
#undef LOADB
#undef MFMA16
}

// ===================== 128x256 8-phase V core =====================
// (R14-R16 structure, passed refcheck.) 512 threads, LDS 96KB.
__device__ __forceinline__ void gemm_v128_core(
    const unsigned short* __restrict__ Ab,   // xb + gm0*1024
    const unsigned short* __restrict__ Bb,   // Wvt + gn0*1024
    unsigned short* lds, f32x4 acc[4][4])
{
    const int tid  = threadIdx.x;
    const int w    = tid >> 6;
    const int lane = tid & 63;

    const int r  = lane >> 3;
    const int s  = lane & 7;
    const int cg = (s ^ r) * 8;

    const int fr    = lane & 15;
    const int quad  = lane >> 4;
    const int sw    = fr & 7;
    const int arow0 = (w >> 2) * 64;
    const int brow0 = (w & 3) * 64;

#define STG_VA(t, mh, buf) do {                                             \
    const int rb_ = (w >> 2) * 64 + (mh) * 32 + (w & 3) * 8;                \
    const unsigned short* g_ = Ab + (long)(rb_ + r) * 1024 + (long)(t) * 64 + cg; \
    unsigned short* d_ = lds + (buf) * 8192 + rb_ * 64;                     \
    GLDS16(g_, d_); } while (0)
#define STG_VB(t, nh, buf) do {                                             \
    const int rb_ = (w >> 1) * 64 + (nh) * 32 + (w & 1) * 16;               \
    const unsigned short* g_ = Bb + (long)(rb_ + r) * 1024 + (long)(t) * 64 + cg; \
    unsigned short* d_ = lds + 16384 + (buf) * 16384 + rb_ * 64;            \
    GLDS16(g_, d_); GLDS16(g_ + 8 * 1024, d_ + 512); } while (0)

    bf16x8 af[2][2], bfA[2][2], bfB[2][2];
#define LOADVA(buf, mh) do {                                                \
    _Pragma("unroll") for (int ks_ = 0; ks_ < 2; ks_++)                     \
    _Pragma("unroll") for (int i_ = 0; i_ < 2; i_++)                        \
        af[i_][ks_] = *(const bf16x8*)&lds[(buf) * 8192 +                   \
            (arow0 + (mh) * 32 + i_ * 16 + fr) * 64 +                       \
            ((ks_ * 4 + quad) ^ sw) * 8]; } while (0)
#define LOADVB(BF, buf, nh) do {                                            \
    _Pragma("unroll") for (int ks_ = 0; ks_ < 2; ks_++)                     \
    _Pragma("unroll") for (int j_ = 0; j_ < 2; j_++)                        \
        BF[j_][ks_] = *(const bf16x8*)&lds[16384 + (buf) * 16384 +          \
            (brow0 + (nh) * 32 + j_ * 16 + fr) * 64 +                       \
            ((ks_ * 4 + quad) ^ sw) * 8]; } while (0)

#define MFMA_V(mh, nh, BF) do {                                             \
    __builtin_amdgcn_s_setprio(1);                                          \
    _Pragma("unroll") for (int ks_ = 0; ks_ < 2; ks_++)                     \
    _Pragma("unroll") for (int i_ = 0; i_ < 2; i_++)                        \
    _Pragma("unroll") for (int j_ = 0; j_ < 2; j_++)                        \
        acc[(mh) * 2 + i_][(nh) * 2 + j_] =                                 \
            __builtin_amdgcn_mfma_f32_16x16x32_bf16(                        \
                af[i_][ks_], BF[j_][ks_],                                   \
                acc[(mh) * 2 + i_][(nh) * 2 + j_], 0, 0, 0);                \
    __builtin_amdgcn_s_setprio(0); } while (0)

#pragma unroll
    for (int i = 0; i < 4; i++)
#pragma unroll
        for (int j = 0; j < 4; j++) acc[i][j] = f32x4{0.f, 0.f, 0.f, 0.f};

    // prologue: buf0 <- tile0 (6 loads); buf1 <- tile1 partial (A-mh0 1, B-nh1 2)
    STG_VA(0, 0, 0); STG_VA(0, 1, 0); STG_VB(0, 0, 0); STG_VB(0, 1, 0);
    STG_VA(1, 0, 1); STG_VB(1, 1, 1);
    asm volatile("s_waitcnt vmcnt(3)" ::: "memory");   // buf0 complete
    BARSYNC;

#pragma unroll 1
    for (int i = 0; i < 8; ++i) {
        const int t1 = 2 * i + 1;
        const int t2 = (2 * i + 2) & 15;   // dummy re-read on last iter (safe)
        const int t3 = (2 * i + 3) & 15;
        // ph1 (buf0, mh0, nh0)
        LOADVA(0, 0); LOADVB(bfA, 0, 0); STG_VB(t1, 0, 1);
        BARSYNC; WAITLGKM; MFMA_V(0, 0, bfA); BARSYNC;
        // ph2 (buf0, mh0, nh1)
        LOADVB(bfB, 0, 1); STG_VA(t1, 1, 1);
        BARSYNC; WAITLGKM; MFMA_V(0, 1, bfB); BARSYNC;
        // ph3 (buf0, mh1, nh1)
        LOADVA(0, 1); STG_VA(t2, 0, 0);
        BARSYNC; WAITLGKM; MFMA_V(1, 1, bfB); BARSYNC;
        // ph4 (buf0, mh1, nh0) reuses bfA + drain: buf1 <- t1 complete
        STG_VB(t2, 1, 0);
        BARSYNC; MFMA_V(1, 0, bfA);
        asm volatile("s_waitcnt vmcnt(3)" ::: "memory"); BARSYNC;
        // ph5 (buf1, mh0, nh0)
        LOADVA(1, 0); LOADVB(bfA, 1, 0); STG_VA(t2, 1, 0);
        BARSYNC; WAITLGKM; MFMA_V(0, 0, bfA); BARSYNC;
        // ph6 (buf1, mh0, nh1)
        LOADVB(bfB, 1, 1); STG_VB(t2, 0, 0);
        BARSYNC; WAITLGKM; MFMA_V(0, 1, bfB); BARSYNC;
        // ph7 (buf1, mh1, nh1)
        LOADVA(1, 1); STG_VA(t3, 0, 1);
        BARSYNC; WAITLGKM; MFMA_V(1, 1, bfB); BARSYNC;
        // ph8 (buf1, mh1, nh0) reuses bfA + drain: buf0 <- t2 complete
        STG_VB(t3, 1, 1);
        BARSYNC; MFMA_V(1, 0, bfA);
        asm volatile("s_waitcnt vmcnt(3)" ::: "memory"); BARSYNC;
    }
    asm volatile("s_waitcnt vmcnt(0)" ::: "memory");   // drain dummy stages

#undef STG_VA
#undef STG_VB
#undef LOADVA
#undef LOADVB
#undef MFMA_V
}

// ===================== 256x128 8-phase PV core =====================
// (R13-R15 structure, passed refcheck.) LDS 96KB. WAITV(3) at ph4/ph8.
__device__ __forceinline__ void pv256_core(
    const unsigned short* __restrict__ Ab,   // P + bz*4M + gm0*2048
    const unsigned short* __restrict__ Bb,   // Vt + gn0*8192 + bz*2048
    unsigned short* lds, f32x4 acc[8][2])
{
    const int tid  = threadIdx.x;
    const int w    = tid >> 6;
    const int lane = tid & 63;

    const int r  = lane >> 3;
    const int s  = lane & 7;
    const int cg = (s ^ r) * 8;

    const int fr    = lane & 15;
    const int quad  = lane >> 4;
    const int sw    = fr & 7;
    const int arow0 = (w >> 2) * 128;
    const int brow0 = (w & 3) * 32;

#define STG_PA(t, mh, buf) do {                                             \
    const int rb_ = (w >> 2) * 128 + (mh) * 64 + (w & 3) * 16;              \
    const unsigned short* g_ = Ab + (long)(rb_ + r) * 2048 + (long)(t) * 64 + cg; \
    unsigned short* d_ = lds + (buf) * 16384 + rb_ * 64;                    \
    GLDS16(g_, d_); GLDS16(g_ + 8 * 2048, d_ + 512); } while (0)
#define STG_PB(t, nh, buf) do {                                             \
    const int rb_ = (w & 3) * 32 + (nh) * 16 + (w >> 2) * 8;                \
    const unsigned short* g_ = Bb + (long)(rb_ + r) * 8192 + (long)(t) * 64 + cg; \
    unsigned short* d_ = lds + 32768 + (buf) * 8192 + rb_ * 64;             \
    GLDS16(g_, d_); } while (0)

    bf16x8 af[4][2], bfA[2], bfB[2];
#define LOADPA(buf, mh) do {                                                \
    _Pragma("unroll") for (int ks_ = 0; ks_ < 2; ks_++)                     \
    _Pragma("unroll") for (int i_ = 0; i_ < 4; i_++)                        \
        af[i_][ks_] = *(const bf16x8*)&lds[(buf) * 16384 +                  \
            (arow0 + (mh) * 64 + i_ * 16 + fr) * 64 +                       \
            ((ks_ * 4 + quad) ^ sw) * 8]; } while (0)
#define LOADPB(BF, buf, nh) do {                                            \
    _Pragma("unroll") for (int ks_ = 0; ks_ < 2; ks_++)                     \
        BF[ks_] = *(const bf16x8*)&lds[32768 + (buf) * 8192 +               \
            (brow0 + (nh) * 16 + fr) * 64 +                                 \
            ((ks_ * 4 + quad) ^ sw) * 8]; } while (0)

#define MFMA8(mh, nh, BF) do {                                              \
    __builtin_amdgcn_s_setprio(1);                                          \
    _Pragma("unroll") for (int ks_ = 0; ks_ < 2; ks_++)                     \
    _Pragma("unroll") for (int i_ = 0; i_ < 4; i_++)                        \
        acc[(mh) * 4 + i_][nh] = __builtin_amdgcn_mfma_f32_16x16x32_bf16(   \
            af[i_][ks_], BF[ks_], acc[(mh) * 4 + i_][nh], 0, 0, 0);         \
    __builtin_amdgcn_s_setprio(0); } while (0)

#pragma unroll
    for (int i = 0; i < 8; i++)
#pragma unroll
        for (int j = 0; j < 2; j++) acc[i][j] = f32x4{0.f, 0.f, 0.f, 0.f};

    // prologue: buf0 <- tile0 (6 loads); buf1 <- tile1 partial (A-mh0 2, B-nh1 1)
    STG_PA(0, 0, 0); STG_PA(0, 1, 0); STG_PB(0, 0, 0); STG_PB(0, 1, 0);
    STG_PA(1, 0, 1); STG_PB(1, 1, 1);
    asm volatile("s_waitcnt vmcnt(3)" ::: "memory");   // buf0 complete
    BARSYNC;

#pragma unroll 1
    for (int i = 0; i < 16; ++i) {
        const int t1 = 2 * i + 1;
        const int t2 = (2 * i + 2) & 31;   // dummy re-read on last iter (safe)
        const int t3 = (2 * i + 3) & 31;
        // ph1 (buf0, mh0, nh0)
        LOADPA(0, 0); LOADPB(bfA, 0, 0); STG_PB(t1, 0, 1);
        BARSYNC; WAITLGKM; MFMA8(0, 0, bfA); BARSYNC;
        // ph2 (buf0, mh0, nh1)
        LOADPB(bfB, 0, 1); STG_PA(t1, 1, 1);
        BARSYNC; WAITLGKM; MFMA8(0, 1, bfB); BARSYNC;
        // ph3 (buf0, mh1, nh1)
        LOADPA(0, 1); STG_PA(t2, 0, 0);
        BARSYNC; WAITLGKM; MFMA8(1, 1, bfB); BARSYNC;
        // ph4 (buf0, mh1, nh0) reuses bfA + drain: buf1 <- t1 complete
        STG_PB(t2, 1, 0);
        BARSYNC; MFMA8(1, 0, bfA);
        asm volatile("s_waitcnt vmcnt(3)" ::: "memory"); BARSYNC;
        // ph5 (buf1, mh0, nh0)
        LOADPA(1, 0); LOADPB(bfA, 1, 0); STG_PA(t2, 1, 0);
        BARSYNC; WAITLGKM; MFMA8(0, 0, bfA); BARSYNC;
        // ph6 (buf1, mh0, nh1)
        LOADPB(bfB, 1, 1); STG_PB(t2, 0, 0);
        BARSYNC; WAITLGKM; MFMA8(0, 1, bfB); BARSYNC;
        // ph7 (buf1, mh1, nh1)
        LOADPA(1, 1); STG_PA(t3, 0, 1);
        BARSYNC; WAITLGKM; MFMA8(1, 1, bfB); BARSYNC;
        // ph8 (buf1, mh1, nh0) reuses bfA + drain: buf0 <- t2 complete
        STG_PB(t3, 1, 1);
        BARSYNC; MFMA8(1, 0, bfA);
        asm volatile("s_waitcnt vmcnt(3)" ::: "memory"); BARSYNC;
    }
    asm volatile("s_waitcnt vmcnt(0)" ::: "memory");   // drain dummy stages

#undef STG_PA
#undef STG_PB
#undef LOADPA
#undef LOADPB
#undef MFMA8
}

// ---------------- merged Q/K + V GEMM (512 blocks, R16 passed) -------------
// blocks 0-255: qk (swapped: A=W rows f, B=x rows m; ushort4 -> QK[m][f]).
// blocks 256-511: v (Vt[e*8192+m]). Independent ops.
__global__ __launch_bounds__(512, 2) void gemm_qkv_split(
    const unsigned short* __restrict__ X, const unsigned short* __restrict__ W,
    unsigned short* __restrict__ QK, unsigned short* __restrict__ Vt)
{
    __shared__ unsigned short lds[65536];
    const int tid = threadIdx.x;
    const int w = tid >> 6, lane = tid & 63;
    const int fr = lane & 15, quad = lane >> 4;

    if (blockIdx.x < 256) {
        const int orig = blockIdx.x;
        const int xcd  = orig & 7;
        const int pos  = orig >> 3;           // 0..31
        const long gm0 = (long)(pos >> 2) * 256;            // feature f
        const long gn0 = (long)(xcd * 4 + (pos & 3)) * 256; // token m

        f32x4 acc[8][4];
        gemm256_core(W + gm0 * 1024, X + gn0 * 1024, 1024, lds, acc);

        const int wm = (w >> 2) * 128, wn = (w & 3) * 64;
#pragma unroll
        for (int mi = 0; mi < 8; mi++) {
            const long rb = gm0 + wm + (mi >> 2) * 64 + (mi & 3) * 16 + quad * 4;  // f
#pragma unroll
            for (int n = 0; n < 4; n++) {
                const long cb = gn0 + wn + n * 16 + fr;                            // m
                ushort4 o;
                o.x = f2bf(acc[mi][n][0]);
                o.y = f2bf(acc[mi][n][1]);
                o.z = f2bf(acc[mi][n][2]);
                o.w = f2bf(acc[mi][n][3]);
                *(ushort4*)&QK[cb * 2048L + rb] = o;
            }
        }
    } else {
        const int orig = blockIdx.x - 256;
        const int xcd  = orig & 7;
        const int pos  = orig >> 3;           // 0..31
        const long gm0 = (long)(xcd * 8 + (pos & 7)) * 128;
        const long gn0 = (long)(pos >> 3) * 256;

        f32x4 acc[4][4];
        gemm_v128_core(X + gm0 * 1024, W + 2 * 1024 * 1024L + gn0 * 1024, lds, acc);

        const int wm = (w >> 2) * 64, wn = (w & 3) * 64;
#pragma unroll
        for (int ai = 0; ai < 4; ai++) {
            const long rb = gm0 + wm + ai * 16 + quad * 4;
#pragma unroll
            for (int aj = 0; aj < 4; aj++) {
                const long ce = gn0 + wn + aj * 16 + fr;
                ushort4 o;
                o.x = f2bf(acc[ai][aj][0]);
                o.y = f2bf(acc[ai][aj][1]);
                o.z = f2bf(acc[ai][aj][2]);
                o.w = f2bf(acc[ai][aj][3]);
                *(ushort4*)&Vt[ce * 8192L + rb] = o;
            }
        }
    }
}

// ------------- scores GEMM (swapped: A=Q rows i, B=K rows j; R15 passed) ---
// C[i,j]; ushort4 -> P[j*2048+i]; lane-local l[j] sums.
__global__ __launch_bounds__(512, 2) void gemm_scores256(
    const unsigned short* __restrict__ QKb, unsigned short* __restrict__ P,
    float* __restrict__ l)
{
    __shared__ unsigned short lds[65536];
    const int orig = blockIdx.x;
    const int xcd  = orig & 7;
    const int pos  = orig >> 3;           // 0..31
    const int bz   = xcd >> 1;
    const long gm0 = (long)((xcd & 1) * 4 + (pos >> 3)) * 256;  // i (Q rows)
    const long gn0 = (long)(pos & 7) * 256;                     // j (K rows)

    const unsigned short* Ab = QKb + (long)bz * 2048 * 2048 + gm0 * 2048;         // Q
    const unsigned short* Bb = QKb + (long)bz * 2048 * 2048 + 1024 + gn0 * 2048;  // K

    f32x4 acc[8][4];
    gemm256_core(Ab, Bb, 2048, lds, acc);

    const int tid = threadIdx.x;
    const int w = tid >> 6, lane = tid & 63;
    const int fr = lane & 15, quad = lane >> 4;
    const int wm = (w >> 2) * 128, wn = (w & 3) * 64;

    unsigned short* Pb = P + (long)bz * 2048 * 2048;
    float* lb = l + (long)bz * 2048;
    const float scale = 1.0f / 32.0f;

    float colsum[4] = {0.f, 0.f, 0.f, 0.f};
#pragma unroll
    for (int mi = 0; mi < 8; mi++) {
        const long rb = gm0 + wm + (mi >> 2) * 64 + (mi & 3) * 16 + quad * 4;  // i
#pragma unroll
        for (int n = 0; n < 4; n++) {
            const long cb = gn0 + wn + n * 16 + fr;                            // j
            float e0 = __expf(acc[mi][n][0] * scale);
            float e1 = __expf(acc[mi][n][1] * scale);
            float e2 = __expf(acc[mi][n][2] * scale);
            float e3 = __expf(acc[mi][n][3] * scale);
            colsum[n] += (e0 + e1) + (e2 + e3);
            ushort4 o;
            o.x = f2bf(e0); o.y = f2bf(e1); o.z = f2bf(e2); o.w = f2bf(e3);
            *(ushort4*)&Pb[cb * 2048L + rb] = o;
        }
    }
    // combine the 4 quads (same j across quads), then one atomic per (w, fr, n)
#pragma unroll
    for (int n = 0; n < 4; n++) {
        colsum[n] += __shfl_xor(colsum[n], 16);
        colsum[n] += __shfl_xor(colsum[n], 32);
    }
    if (quad == 0) {
#pragma unroll
        for (int n = 0; n < 4; n++)
            atomicAdd(&lb[gn0 + wn + n * 16 + fr], colsum[n]);
    }
}

// ---------------- PV GEMM (256x128 8-phase; R13-R15 passed) ----------------
// out_b[j,e] = (sum_i P'_b[j,i] * Vt[e, b*2048+i]) / l[b][j]
// Grid 256 = exact single round. XCD swizzle: bz = xcd>>1.
__global__ __launch_bounds__(512, 2) void gemm_pv256(
    const unsigned short* __restrict__ P, const unsigned short* __restrict__ Vt,
    const float* __restrict__ l, float* __restrict__ out)
{
    __shared__ unsigned short lds[49152];   // 96 KB
    const int orig = blockIdx.x;
    const int xcd  = orig & 7;
    const int pos  = orig >> 3;           // 0..31
    const int bz   = xcd >> 1;
    const long gm0 = (long)((xcd & 1) * 4 + (pos >> 3)) * 256;  // j
    const long gn0 = (long)(pos & 7) * 128;                     // e

    const unsigned short* Ab = P + (long)bz * 2048 * 2048 + gm0 * 2048;
    const unsigned short* Bb = Vt + gn0 * 8192 + (long)bz * 2048;

    f32x4 acc[8][2];
    pv256_core(Ab, Bb, lds, acc);

    const int tid = threadIdx.x;
    const int w = tid >> 6, lane = tid & 63;
    const int fr = lane & 15, quad = lane >> 4;
    const int wm = (w >> 2) * 128, wn = (w & 3) * 32;

    float* Ob = out + (long)bz * 2048 * 1024;
    const float* lb = l + (long)bz * 2048;
#pragma unroll
    for (int mi = 0; mi < 8; mi++) {
        const long rb = gm0 + wm + (mi >> 2) * 64 + (mi & 3) * 16 + quad * 4;
        float inv[4];
#pragma unroll
        for (int rr = 0; rr < 4; rr++) inv[rr] = 1.0f / lb[rb + rr];
#pragma unroll
        for (int nj = 0; nj < 2; nj++) {
            const long cb = gn0 + wn + nj * 16 + fr;
#pragma unroll
            for (int rr = 0; rr < 4; rr++)
                Ob[(rb + rr) * 1024L + cb] = acc[mi][nj][rr] * inv[rr];
        }
    }
}

// Fused prep: [0,8192) convert x; [8192,8192+3072) transpose weights;
// block 11264 zeroes l (8192 floats).
__global__ __launch_bounds__(256) void prep(
    const float* __restrict__ x,
    const float* __restrict__ Wq, const float* __restrict__ Wk,
    const float* __restrict__ Wv,
    unsigned short* __restrict__ xb, unsigned short* __restrict__ Wqkvt,
    float* __restrict__ l)
{
    __shared__ float t[32][33];
    const int b = blockIdx.x;
    const int tid = threadIdx.x;
    if (b < 8192) {
        int i = b * 256 + tid;
        float4 v = ((const float4*)x)[i];
        ushort4 o;
        o.x = f2bf(v.x); o.y = f2bf(v.y); o.z = f2bf(v.z); o.w = f2bf(v.w);
        ((ushort4*)xb)[i] = o;
        return;
    }
    if (b == 8192 + 3072) {
        float4 z = {0.f, 0.f, 0.f, 0.f};
#pragma unroll
        for (int i = 0; i < 8; i++)
            ((float4*)l)[tid * 8 + i] = z;
        return;
    }
    int tix = b - 8192;
    const int w = tix >> 10;
    tix &= 1023;
    const float* W = (w == 0) ? Wq : (w == 1) ? Wk : Wv;
    unsigned short* Wt = Wqkvt + (long)w * 1024 * 1024;
    const int bx = (tix & 31) * 32;
    const int by = (tix >> 5) * 32;
    const int tx = tid & 31;
    const int ty = (tid >> 5) * 4;
#pragma unroll
    for (int j = 0; j < 4; j++)
        t[ty + j][tx] = W[(long)(by + ty + j) * 1024 + bx + tx];
    __syncthreads();
#pragma unroll
    for (int j = 0; j < 4; j++)
        Wt[(long)(bx + ty + j) * 1024 + by + tx] = f2bf(t[tx][ty + j]);
}

extern "C" void kernel_launch(void* const* d_in, const int* in_sizes, int n_in,
                              void* d_out, int out_size, void* d_ws,
                              size_t ws_size, hipStream_t stream)
{
    const float* x  = (const float*)d_in[0];
    const float* Wq = (const float*)d_in[1];
    const float* Wk = (const float*)d_in[2];
    const float* Wv = (const float*)d_in[3];
    float* out = (float*)d_out;

    const long M1 = 1024 * 1024;
    unsigned short* u     = (unsigned short*)d_ws;
    unsigned short* xb    = u;                  // 8M
    unsigned short* Wqkvt = u + 8 * M1;         // 3M
    unsigned short* QKb   = Wqkvt + 3 * M1;     // 16M [8192 x 2048]
    unsigned short* Vtb   = QKb + 16 * M1;      // 8M  [1024 x 8192]
    unsigned short* Pb    = Vtb + 8 * M1;       // 16M [4 x 2048 x 2048]
    float* l              = (float*)(Pb + 16 * M1);  // 8192 f32

    prep<<<dim3(8192 + 3072 + 1), dim3(256), 0, stream>>>(x, Wq, Wk, Wv, xb, Wqkvt, l);

    // Q/K (blocks 0-255) + V (blocks 256-511) in one kernel
    gemm_qkv_split<<<dim3(512), dim3(512), 0, stream>>>(xb, Wqkvt, QKb, Vtb);

    // scores: C[i,j] = Q_i.K_j, exp, transposed-store to P[j][i], l[j] sums
    gemm_scores256<<<dim3(256), dim3(512), 0, stream>>>(QKb, Pb, l);

    // out = (P' @ V) / l, 256x128 8-phase, 256 blocks exact
    gemm_pv256<<<dim3(256), dim3(512), 0, stream>>>(Pb, Vtb, l, out);
}